// Round 7
// baseline (327.197 us; speedup 1.0000x reference)
//
#include <hip/hip_runtime.h>

#define NNODES 50000
#define NEDGES 640000
#define D 128

typedef unsigned short u16;
typedef unsigned int u32;
typedef __bf16 bf16x8 __attribute__((ext_vector_type(8)));
typedef float f32x4 __attribute__((ext_vector_type(4)));
union AB { uint4 u4; bf16x8 f; };

__device__ __forceinline__ u16 f2b(float f) {
    u32 u = __float_as_uint(f);
    return (u16)((u + 0x7fffu + ((u >> 16) & 1u)) >> 16);
}
__device__ __forceinline__ u32 pack2(float lo, float hi) {
    return (u32)f2b(lo) | ((u32)f2b(hi) << 16);
}
__device__ __forceinline__ float blo(u32 v) { return __uint_as_float(v << 16); }
__device__ __forceinline__ float bhi(u32 v) { return __uint_as_float(v & 0xffff0000u); }

__device__ __forceinline__ void acc8(float* a, uint4 v) {
    a[0] += blo(v.x); a[1] += bhi(v.x);
    a[2] += blo(v.y); a[3] += bhi(v.y);
    a[4] += blo(v.z); a[5] += bhi(v.z);
    a[6] += blo(v.w); a[7] += bhi(v.w);
}

// ---------------- weight prep + x conversion (float4) + edge histogram ----------------
__global__ void k_prep(const float* __restrict__ W1, const float* __restrict__ W2,
                       const float* __restrict__ fw, const float* __restrict__ x,
                       const int* __restrict__ dst,
                       u16* __restrict__ wT1, u16* __restrict__ wT2,
                       u16* __restrict__ fwTc, uint2* __restrict__ xb,
                       int* __restrict__ cnt, int* __restrict__ epos) {
    int idx = blockIdx.x * 256 + threadIdx.x;
    if (idx < 3 * 16384) {
        int l = idx >> 14, r = idx & 16383, n = r >> 7, k = r & 127;
        wT1[idx] = f2b(W1[l * 16384 + k * 128 + n]);
        wT2[idx] = f2b(W2[l * 16384 + k * 128 + n]);
    }
    if (idx < 4 * 16384) {
        int ch = idx >> 14, r = idx & 16383, n = r >> 7, k = r & 127;
        fwTc[idx] = f2b(fw[(ch * 128 + k) * 128 + n]);
    }
    if (idx < NEDGES) {
        epos[idx] = atomicAdd(&cnt[dst[idx]], 1);
    }
    if (idx < NNODES * 32) {  // float4 per thread: 16B load, 8B store
        float4 v = ((const float4*)x)[idx];
        xb[idx] = make_uint2(pack2(v.x, v.y), pack2(v.z, v.w));
    }
}

// ---------------- scan: per-block scan + last-block scans the block sums ----------------
// rp stays RAW (per-block exclusive prefix); consumers add bsum[i>>8] on the fly,
// eliminating the k_add pass entirely.
__global__ void k_scan1(const int* __restrict__ cnt, int* __restrict__ rp,
                        int* __restrict__ bsum, int* __restrict__ counter) {
    __shared__ int s[256];
    __shared__ int lastBlk;
    int tid = threadIdx.x;
    int i = blockIdx.x * 256 + tid;
    int v = (i < NNODES) ? cnt[i] : 0;
    s[tid] = v;
    __syncthreads();
    for (int off = 1; off < 256; off <<= 1) {
        int t = (tid >= off) ? s[tid - off] : 0;
        __syncthreads();
        s[tid] += t;
        __syncthreads();
    }
    if (i < NNODES) rp[i] = s[tid] - v;
    if (tid == 255)
        __hip_atomic_store(&bsum[blockIdx.x], s[255], __ATOMIC_RELEASE,
                           __HIP_MEMORY_SCOPE_AGENT);
    __syncthreads();  // bsum store issued; s free for reuse
    if (tid == 0) {
        int n = __hip_atomic_fetch_add(counter, 1, __ATOMIC_ACQ_REL,
                                       __HIP_MEMORY_SCOPE_AGENT);
        lastBlk = (n == (int)gridDim.x - 1);
    }
    __syncthreads();
    if (lastBlk) {  // whole last block: exclusive-scan bsum[0..nb)
        int nb = gridDim.x;
        int v2 = (tid < nb)
                     ? __hip_atomic_load(&bsum[tid], __ATOMIC_ACQUIRE,
                                         __HIP_MEMORY_SCOPE_AGENT)
                     : 0;
        s[tid] = v2;
        __syncthreads();
        for (int off = 1; off < 256; off <<= 1) {
            int t = (tid >= off) ? s[tid - off] : 0;
            __syncthreads();
            s[tid] += t;
            __syncthreads();
        }
        if (tid < nb) bsum[tid] = s[tid] - v2;
    }
}

// ---------------- scatter: pure store, no atomic; final rp = rp[d]+bsum[d>>8] ----
__global__ void k_scatter(const int* __restrict__ src, const int* __restrict__ dst,
                          const int* __restrict__ rp, const int* __restrict__ bsum,
                          const int* __restrict__ epos, int* __restrict__ srcs) {
    int e = blockIdx.x * 256 + threadIdx.x;
    if (e < NEDGES) {
        int d = dst[e];
        srcs[rp[d] + bsum[d >> 8] + epos[e]] = src[e];
    }
}

// ---------------- aggregation: standalone, high-occupancy, 8-deep gather ----------------
// 16 lanes/node, one node per group, grid = 50000*16/256 = 3125 (exact).
// __launch_bounds__(256,8): pin <=64 VGPR so the gather runs at 8 waves/SIMD
// (32 waves/CU) — the 64-VGPR occupancy cliff is the only free lever left here.
__launch_bounds__(256, 8)
__global__ void k_agg(const uint4* __restrict__ h4, const int* __restrict__ rp,
                      const int* __restrict__ bsum, const int* __restrict__ srcs,
                      const float* __restrict__ epsp, uint4* __restrict__ z4) {
    int tid = threadIdx.x;
    int c = tid & 15;                          // 16B chunk of the 256B row
    int node = (blockIdx.x * 256 + tid) >> 4;  // exact coverage
    int gbase = tid & 48;                      // group base lane within wave
    float sc = 1.0f + epsp[0];

    uint4 sv = h4[node * 16 + c];
    float acc[8];
    acc[0] = sc * blo(sv.x); acc[1] = sc * bhi(sv.x);
    acc[2] = sc * blo(sv.y); acc[3] = sc * bhi(sv.y);
    acc[4] = sc * blo(sv.z); acc[5] = sc * bhi(sv.z);
    acc[6] = sc * blo(sv.w); acc[7] = sc * bhi(sv.w);

    int beg = rp[node] + bsum[node >> 8];
    int end = (node + 1 == NNODES) ? NEDGES : rp[node + 1] + bsum[(node + 1) >> 8];
    for (int base = beg; base < end; base += 16) {
        int n = end - base; if (n > 16) n = 16;
        int myidx = (base + c < end) ? srcs[base + c] : 0;
        int j = 0;
        for (; j + 8 <= n; j += 8) {
            int s0 = __shfl(myidx, gbase + j + 0, 64);
            int s1 = __shfl(myidx, gbase + j + 1, 64);
            int s2 = __shfl(myidx, gbase + j + 2, 64);
            int s3 = __shfl(myidx, gbase + j + 3, 64);
            int s4 = __shfl(myidx, gbase + j + 4, 64);
            int s5 = __shfl(myidx, gbase + j + 5, 64);
            int s6 = __shfl(myidx, gbase + j + 6, 64);
            int s7 = __shfl(myidx, gbase + j + 7, 64);
            uint4 v0 = h4[s0 * 16 + c]; uint4 v1 = h4[s1 * 16 + c];
            uint4 v2 = h4[s2 * 16 + c]; uint4 v3 = h4[s3 * 16 + c];
            uint4 v4 = h4[s4 * 16 + c]; uint4 v5 = h4[s5 * 16 + c];
            uint4 v6 = h4[s6 * 16 + c]; uint4 v7 = h4[s7 * 16 + c];
            acc8(acc, v0); acc8(acc, v1); acc8(acc, v2); acc8(acc, v3);
            acc8(acc, v4); acc8(acc, v5); acc8(acc, v6); acc8(acc, v7);
        }
        for (; j + 4 <= n; j += 4) {
            int s0 = __shfl(myidx, gbase + j + 0, 64);
            int s1 = __shfl(myidx, gbase + j + 1, 64);
            int s2 = __shfl(myidx, gbase + j + 2, 64);
            int s3 = __shfl(myidx, gbase + j + 3, 64);
            uint4 v0 = h4[s0 * 16 + c]; uint4 v1 = h4[s1 * 16 + c];
            uint4 v2 = h4[s2 * 16 + c]; uint4 v3 = h4[s3 * 16 + c];
            acc8(acc, v0); acc8(acc, v1); acc8(acc, v2); acc8(acc, v3);
        }
        for (; j < n; ++j) {
            int s0 = __shfl(myidx, gbase + j, 64);
            uint4 v0 = h4[s0 * 16 + c];
            acc8(acc, v0);
        }
    }

    uint4 o;
    o.x = pack2(acc[0], acc[1]); o.y = pack2(acc[2], acc[3]);
    o.z = pack2(acc[4], acc[5]); o.w = pack2(acc[6], acc[7]);
    z4[node * 16 + c] = o;
}

// ---------------- MLP via MFMA, XOR-swizzled LDS; FINAL fuses output projection ----
template <bool FINAL>
__launch_bounds__(256, 2)
__global__ void k_mlp(const u16* __restrict__ A, const u16* __restrict__ wT1g,
                      const float* __restrict__ b1, const u16* __restrict__ wT2g,
                      const float* __restrict__ b2, u16* __restrict__ H,
                      const u16* __restrict__ xbg, const u16* __restrict__ h1g,
                      const u16* __restrict__ h2g, const u16* __restrict__ fwTc,
                      const float* __restrict__ fb, float* __restrict__ out) {
    __shared__ u16 Tb[128 * 128];    // 32 KB
    __shared__ u16 wbuf[128 * 128];  // 32 KB
    uint4* Tb4 = (uint4*)Tb;
    uint4* wb4 = (uint4*)wbuf;
    int tid = threadIdx.x;
    int r0 = blockIdx.x * 128;
    int wave = tid >> 6, lane = tid & 63, l16 = lane & 15, quad = lane >> 4;

    // stage W1^T (swizzled)
    {
        const uint4* g = (const uint4*)wT1g;
        for (int i = tid; i < 2048; i += 256) {
            int n = i >> 4, ch = i & 15;
            wb4[n * 16 + ((ch + n) & 15)] = g[i];
        }
    }

    // A-fragments straight from global (no cross-wave reuse)
    AB a[2][4];
#pragma unroll
    for (int s = 0; s < 2; ++s) {
        int row = r0 + wave * 32 + s * 16 + l16;
#pragma unroll
        for (int kb = 0; kb < 4; ++kb) {
            if (row < NNODES)
                a[s][kb].u4 = *(const uint4*)&A[row * 128 + kb * 32 + quad * 8];
            else
                a[s][kb].u4 = make_uint4(0, 0, 0, 0);
        }
    }
    __syncthreads();

    f32x4 acc[2][8];
#pragma unroll
    for (int col = 0; col < 8; ++col) {
        float bv = b1[col * 16 + l16];
        acc[0][col] = (f32x4){bv, bv, bv, bv};
        acc[1][col] = (f32x4){bv, bv, bv, bv};
    }
#pragma unroll
    for (int col = 0; col < 8; ++col) {
#pragma unroll
        for (int kb = 0; kb < 4; ++kb) {
            AB b;
            int n = col * 16 + l16;
            b.u4 = wb4[n * 16 + ((kb * 4 + quad + n) & 15)];
            acc[0][col] = __builtin_amdgcn_mfma_f32_16x16x32_bf16(a[0][kb].f, b.f, acc[0][col], 0, 0, 0);
            acc[1][col] = __builtin_amdgcn_mfma_f32_16x16x32_bf16(a[1][kb].f, b.f, acc[1][col], 0, 0, 0);
        }
    }

    // T = relu -> Tb (swizzled scalar u16 stores)
#pragma unroll
    for (int s = 0; s < 2; ++s)
#pragma unroll
        for (int col = 0; col < 8; ++col)
#pragma unroll
            for (int r = 0; r < 4; ++r) {
                int row = wave * 32 + s * 16 + quad * 4 + r;
                int kcol = col * 16 + l16;
                int ch = kcol >> 3;
                Tb[row * 128 + ((ch + row) & 15) * 8 + (kcol & 7)] =
                    f2b(fmaxf(acc[s][col][r], 0.f));
            }
    __syncthreads();

    // stage W2^T (swizzled, overwrite wbuf)
    {
        const uint4* g = (const uint4*)wT2g;
        for (int i = tid; i < 2048; i += 256) {
            int n = i >> 4, ch = i & 15;
            wb4[n * 16 + ((ch + n) & 15)] = g[i];
        }
    }
    AB a2[2][4];
#pragma unroll
    for (int s = 0; s < 2; ++s) {
        int m = wave * 32 + s * 16 + l16;
#pragma unroll
        for (int kb = 0; kb < 4; ++kb)
            a2[s][kb].u4 = Tb4[m * 16 + ((kb * 4 + quad + m) & 15)];
    }
    __syncthreads();  // wbuf (W2) ready; Tb reads drained

#pragma unroll
    for (int col = 0; col < 8; ++col) {
        float bv = b2[col * 16 + l16];
        acc[0][col] = (f32x4){bv, bv, bv, bv};
        acc[1][col] = (f32x4){bv, bv, bv, bv};
    }
#pragma unroll
    for (int col = 0; col < 8; ++col) {
#pragma unroll
        for (int kb = 0; kb < 4; ++kb) {
            AB b;
            int n = col * 16 + l16;
            b.u4 = wb4[n * 16 + ((kb * 4 + quad + n) & 15)];
            acc[0][col] = __builtin_amdgcn_mfma_f32_16x16x32_bf16(a2[0][kb].f, b.f, acc[0][col], 0, 0, 0);
            acc[1][col] = __builtin_amdgcn_mfma_f32_16x16x32_bf16(a2[1][kb].f, b.f, acc[1][col], 0, 0, 0);
        }
    }

    // h = relu -> Tb (Tb reads a2 drained at pre-GEMM2 barrier; GEMM2 reads only wbuf)
#pragma unroll
    for (int s = 0; s < 2; ++s)
#pragma unroll
        for (int col = 0; col < 8; ++col)
#pragma unroll
            for (int r = 0; r < 4; ++r) {
                int row = wave * 32 + s * 16 + quad * 4 + r;
                int kcol = col * 16 + l16;
                int ch = kcol >> 3;
                Tb[row * 128 + ((ch + row) & 15) * 8 + (kcol & 7)] =
                    f2b(fmaxf(acc[s][col][r], 0.f));
            }

    if constexpr (!FINAL) {
        __syncthreads();  // Tb (h) ready
        // coalesced copy Tb -> H (de-swizzle); stays cached (read by next k_agg)
        for (int i = tid; i < 2048; i += 256) {
            int r = i >> 4, ch = i & 15;
            int grow = r0 + r;
            if (grow < NNODES)
                *(uint4*)&H[grow * 128 + ch * 8] = Tb4[r * 16 + ((ch + r) & 15)];
        }
    } else {
        // ---- fused final projection: out = concat(x,h1,h2,h3) @ fw + fb ----
#pragma unroll
        for (int col = 0; col < 8; ++col) {
            float bv = fb[col * 16 + l16];
            acc[0][col] = (f32x4){bv, bv, bv, bv};
            acc[1][col] = (f32x4){bv, bv, bv, bv};
        }
        const u16* chin[3] = {xbg, h1g, h2g};
        AB afN[2][4];
#pragma unroll
        for (int s = 0; s < 2; ++s) {  // prefetch chunk 0 (xb)
            int row = r0 + wave * 32 + s * 16 + l16;
#pragma unroll
            for (int kb = 0; kb < 4; ++kb)
                afN[s][kb].u4 = (row < NNODES)
                                    ? *(const uint4*)&xbg[row * 128 + kb * 32 + quad * 8]
                                    : make_uint4(0, 0, 0, 0);
        }
#pragma unroll
        for (int chn = 0; chn < 4; ++chn) {
            __syncthreads();  // prev wbuf MFMA reads drained; (chn0) Tb h3 stores visible
            {
                const uint4* g = (const uint4*)(fwTc + chn * 16384);
                for (int i = tid; i < 2048; i += 256) {
                    int n = i >> 4, ch = i & 15;
                    wb4[n * 16 + ((ch + n) & 15)] = g[i];
                }
            }
            AB af[2][4];
#pragma unroll
            for (int s = 0; s < 2; ++s)
#pragma unroll
                for (int kb = 0; kb < 4; ++kb) af[s][kb] = afN[s][kb];
            if (chn < 2) {  // prefetch next global chunk (h1 or h2)
                const u16* cp = chin[chn + 1];
#pragma unroll
                for (int s = 0; s < 2; ++s) {
                    int row = r0 + wave * 32 + s * 16 + l16;
#pragma unroll
                    for (int kb = 0; kb < 4; ++kb)
                        afN[s][kb].u4 = (row < NNODES)
                                            ? *(const uint4*)&cp[row * 128 + kb * 32 + quad * 8]
                                            : make_uint4(0, 0, 0, 0);
                }
            } else if (chn == 2) {  // prefetch h3 from Tb (stable throughout FINAL)
#pragma unroll
                for (int s = 0; s < 2; ++s) {
                    int m = wave * 32 + s * 16 + l16;
#pragma unroll
                    for (int kb = 0; kb < 4; ++kb)
                        afN[s][kb].u4 = Tb4[m * 16 + ((kb * 4 + quad + m) & 15)];
                }
            }
            __syncthreads();  // wbuf (fw chunk) ready
#pragma unroll
            for (int col = 0; col < 8; ++col) {
#pragma unroll
                for (int kb = 0; kb < 4; ++kb) {
                    AB b;
                    int n = col * 16 + l16;
                    b.u4 = wb4[n * 16 + ((kb * 4 + quad + n) & 15)];
                    acc[0][col] = __builtin_amdgcn_mfma_f32_16x16x32_bf16(af[0][kb].f, b.f, acc[0][col], 0, 0, 0);
                    acc[1][col] = __builtin_amdgcn_mfma_f32_16x16x32_bf16(af[1][kb].f, b.f, acc[1][col], 0, 0, 0);
                }
            }
        }
#pragma unroll
        for (int s = 0; s < 2; ++s)
#pragma unroll
            for (int col = 0; col < 8; ++col)
#pragma unroll
                for (int r = 0; r < 4; ++r) {
                    int row = r0 + wave * 32 + s * 16 + quad * 4 + r;
                    if (row < NNODES)
                        __builtin_nontemporal_store(acc[s][col][r],
                                                    &out[row * 128 + col * 16 + l16]);
                }
    }
}

extern "C" void kernel_launch(void* const* d_in, const int* in_sizes, int n_in,
                              void* d_out, int out_size, void* d_ws, size_t ws_size,
                              hipStream_t stream) {
    const float* x   = (const float*)d_in[0];
    const int*   ei  = (const int*)d_in[1];
    const float* W1  = (const float*)d_in[2];
    const float* b1  = (const float*)d_in[3];
    const float* W2  = (const float*)d_in[4];
    const float* b2  = (const float*)d_in[5];
    const float* eps = (const float*)d_in[6];
    const float* fw  = (const float*)d_in[7];
    const float* fb  = (const float*)d_in[8];
    float* out = (float*)d_out;

    const int* srcA = ei;
    const int* dstA = ei + NEDGES;

    char* p = (char*)d_ws;
    size_t off = 0;
    auto take = [&](size_t bytes) {
        char* r = p + off;
        off = (off + bytes + 255) & ~(size_t)255;
        return r;
    };
    int* rp   = (int*)take((NNODES + 1) * sizeof(int));
    int* cnt  = (int*)take((NNODES + 1) * sizeof(int));  // [NNODES] = scan arrival counter
    int* bsum = (int*)take(256 * sizeof(int));
    int* epos = (int*)take(NEDGES * sizeof(int));
    int* srcs = (int*)take(NEDGES * sizeof(int));
    u16* wT1  = (u16*)take(3 * 16384 * sizeof(u16));
    u16* wT2  = (u16*)take(3 * 16384 * sizeof(u16));
    u16* fwTc = (u16*)take(4 * 16384 * sizeof(u16));
    u16* xb   = (u16*)take((size_t)NNODES * D * sizeof(u16));
    u16* zb   = (u16*)take((size_t)NNODES * D * sizeof(u16));
    u16* hb1  = (u16*)take((size_t)NNODES * D * sizeof(u16));
    u16* hb2  = (u16*)take((size_t)NNODES * D * sizeof(u16));
    (void)ws_size; (void)in_sizes; (void)n_in; (void)out_size;

    (void)hipMemsetAsync(cnt, 0, (NNODES + 1) * sizeof(int), stream);

    int nb = (NNODES + 255) / 256;  // 196
    k_prep<<<(NNODES * 32 + 255) / 256, 256, 0, stream>>>(W1, W2, fw, x, dstA,
                                                          wT1, wT2, fwTc, (uint2*)xb,
                                                          cnt, epos);
    k_scan1<<<nb, 256, 0, stream>>>(cnt, rp, bsum, cnt + NNODES);
    k_scatter<<<(NEDGES + 255) / 256, 256, 0, stream>>>(srcA, dstA, rp, bsum, epos, srcs);

    int gm = (NNODES + 127) / 128;  // 391
    // layer 1
    k_agg<<<NNODES * 16 / 256, 256, 0, stream>>>((const uint4*)xb, rp, bsum, srcs, eps + 0, (uint4*)zb);
    k_mlp<false><<<gm, 256, 0, stream>>>(zb, wT1, b1, wT2, b2, hb1,
                                         nullptr, nullptr, nullptr, nullptr, nullptr, nullptr);
    // layer 2
    k_agg<<<NNODES * 16 / 256, 256, 0, stream>>>((const uint4*)hb1, rp, bsum, srcs, eps + 1, (uint4*)zb);
    k_mlp<false><<<gm, 256, 0, stream>>>(zb, wT1 + 16384, b1 + D, wT2 + 16384, b2 + D, hb2,
                                         nullptr, nullptr, nullptr, nullptr, nullptr, nullptr);
    // layer 3 + fused final projection
    k_agg<<<NNODES * 16 / 256, 256, 0, stream>>>((const uint4*)hb2, rp, bsum, srcs, eps + 2, (uint4*)zb);
    k_mlp<true><<<gm, 256, 0, stream>>>(zb, wT1 + 2 * 16384, b1 + 2 * D,
                                        wT2 + 2 * 16384, b2 + 2 * D, nullptr,
                                        xb, hb1, hb2, fwTc, fb, out);
}

// Round 8
// 261.765 us; speedup vs baseline: 1.2500x; 1.2500x over previous
//
#include <hip/hip_runtime.h>

#define NNODES 50000
#define NEDGES 640000
#define D 128

typedef unsigned short u16;
typedef unsigned int u32;
typedef __bf16 bf16x8 __attribute__((ext_vector_type(8)));
typedef float f32x4 __attribute__((ext_vector_type(4)));
union AB { uint4 u4; bf16x8 f; };

__device__ __forceinline__ u16 f2b(float f) {
    u32 u = __float_as_uint(f);
    return (u16)((u + 0x7fffu + ((u >> 16) & 1u)) >> 16);
}
__device__ __forceinline__ u32 pack2(float lo, float hi) {
    return (u32)f2b(lo) | ((u32)f2b(hi) << 16);
}
__device__ __forceinline__ float blo(u32 v) { return __uint_as_float(v << 16); }
__device__ __forceinline__ float bhi(u32 v) { return __uint_as_float(v & 0xffff0000u); }

__device__ __forceinline__ void acc8(float* a, uint4 v) {
    a[0] += blo(v.x); a[1] += bhi(v.x);
    a[2] += blo(v.y); a[3] += bhi(v.y);
    a[4] += blo(v.z); a[5] += bhi(v.z);
    a[6] += blo(v.w); a[7] += bhi(v.w);
}

// ---------------- weight prep + x conversion (float4) + edge histogram ----------------
__global__ void k_prep(const float* __restrict__ W1, const float* __restrict__ W2,
                       const float* __restrict__ fw, const float* __restrict__ x,
                       const int* __restrict__ dst,
                       u16* __restrict__ wT1, u16* __restrict__ wT2,
                       u16* __restrict__ fwTc, uint2* __restrict__ xb,
                       int* __restrict__ cnt, int* __restrict__ epos) {
    int idx = blockIdx.x * 256 + threadIdx.x;
    if (idx < 3 * 16384) {
        int l = idx >> 14, r = idx & 16383, n = r >> 7, k = r & 127;
        wT1[idx] = f2b(W1[l * 16384 + k * 128 + n]);
        wT2[idx] = f2b(W2[l * 16384 + k * 128 + n]);
    }
    if (idx < 4 * 16384) {
        int ch = idx >> 14, r = idx & 16383, n = r >> 7, k = r & 127;
        fwTc[idx] = f2b(fw[(ch * 128 + k) * 128 + n]);
    }
    if (idx < NEDGES) {
        epos[idx] = atomicAdd(&cnt[dst[idx]], 1);
    }
    if (idx < NNODES * 32) {  // float4 per thread: 16B load, 8B store
        float4 v = ((const float4*)x)[idx];
        xb[idx] = make_uint2(pack2(v.x, v.y), pack2(v.z, v.w));
    }
}

// ---------------- scan: per-block scan + last-block scans the block sums ----------------
// rp stays RAW (per-block exclusive prefix); consumers add bsum[i>>8] on the fly.
__global__ void k_scan1(const int* __restrict__ cnt, int* __restrict__ rp,
                        int* __restrict__ bsum, int* __restrict__ counter) {
    __shared__ int s[256];
    __shared__ int lastBlk;
    int tid = threadIdx.x;
    int i = blockIdx.x * 256 + tid;
    int v = (i < NNODES) ? cnt[i] : 0;
    s[tid] = v;
    __syncthreads();
    for (int off = 1; off < 256; off <<= 1) {
        int t = (tid >= off) ? s[tid - off] : 0;
        __syncthreads();
        s[tid] += t;
        __syncthreads();
    }
    if (i < NNODES) rp[i] = s[tid] - v;
    if (tid == 255)
        __hip_atomic_store(&bsum[blockIdx.x], s[255], __ATOMIC_RELEASE,
                           __HIP_MEMORY_SCOPE_AGENT);
    __syncthreads();  // bsum store issued; s free for reuse
    if (tid == 0) {
        int n = __hip_atomic_fetch_add(counter, 1, __ATOMIC_ACQ_REL,
                                       __HIP_MEMORY_SCOPE_AGENT);
        lastBlk = (n == (int)gridDim.x - 1);
    }
    __syncthreads();
    if (lastBlk) {  // whole last block: exclusive-scan bsum[0..nb)
        int nb = gridDim.x;
        int v2 = (tid < nb)
                     ? __hip_atomic_load(&bsum[tid], __ATOMIC_ACQUIRE,
                                         __HIP_MEMORY_SCOPE_AGENT)
                     : 0;
        s[tid] = v2;
        __syncthreads();
        for (int off = 1; off < 256; off <<= 1) {
            int t = (tid >= off) ? s[tid - off] : 0;
            __syncthreads();
            s[tid] += t;
            __syncthreads();
        }
        if (tid < nb) bsum[tid] = s[tid] - v2;
    }
}

// ---------------- scatter: pure store, no atomic; final rp = rp[d]+bsum[d>>8] ----
__global__ void k_scatter(const int* __restrict__ src, const int* __restrict__ dst,
                          const int* __restrict__ rp, const int* __restrict__ bsum,
                          const int* __restrict__ epos, int* __restrict__ srcs) {
    int e = blockIdx.x * 256 + threadIdx.x;
    if (e < NEDGES) {
        int d = dst[e];
        srcs[rp[d] + bsum[d >> 8] + epos[e]] = src[e];
    }
}

// ---------------- aggregation: 16-deep gather batch, NO launch bound ----------------
// 16 lanes/node, one node per group, grid = 50000*16/256 = 3125 (exact).
// r7 lesson: __launch_bounds__(256,8) forced 32 VGPR -> full pipeline spilled to
// scratch (+65MB/dispatch scratch traffic, 31->48us). Let the allocator choose.
// All 16 batch loads are issued up-front (invalid slots clamp to row 0 = L1-hot);
// accumulation is predicated per-j. Doubles in-flight loads per wave vs 8-deep.
__global__ void k_agg(const uint4* __restrict__ h4, const int* __restrict__ rp,
                      const int* __restrict__ bsum, const int* __restrict__ srcs,
                      const float* __restrict__ epsp, uint4* __restrict__ z4) {
    int tid = threadIdx.x;
    int c = tid & 15;                          // 16B chunk of the 256B row
    int node = (blockIdx.x * 256 + tid) >> 4;  // exact coverage
    int gbase = tid & 48;                      // group base lane within wave
    float sc = 1.0f + epsp[0];

    uint4 sv = h4[node * 16 + c];
    float acc[8];
    acc[0] = sc * blo(sv.x); acc[1] = sc * bhi(sv.x);
    acc[2] = sc * blo(sv.y); acc[3] = sc * bhi(sv.y);
    acc[4] = sc * blo(sv.z); acc[5] = sc * bhi(sv.z);
    acc[6] = sc * blo(sv.w); acc[7] = sc * bhi(sv.w);

    int beg = rp[node] + bsum[node >> 8];
    int end = (node + 1 == NNODES) ? NEDGES : rp[node + 1] + bsum[(node + 1) >> 8];
    for (int base = beg; base < end; base += 16) {
        int n = end - base; if (n > 16) n = 16;
        int myidx = (base + c < end) ? srcs[base + c] : 0;
        uint4 v[16];
#pragma unroll
        for (int j = 0; j < 16; ++j) {
            int s = __shfl(myidx, gbase + j, 64);  // j>=n lanes shuffled idx 0
            v[j] = h4[s * 16 + c];                 // row 0 re-reads are L1-hot
        }
#pragma unroll
        for (int j = 0; j < 16; ++j)
            if (j < n) acc8(acc, v[j]);
    }

    uint4 o;
    o.x = pack2(acc[0], acc[1]); o.y = pack2(acc[2], acc[3]);
    o.z = pack2(acc[4], acc[5]); o.w = pack2(acc[6], acc[7]);
    z4[node * 16 + c] = o;
}

// ---------------- MLP via MFMA, XOR-swizzled LDS; FINAL fuses output projection ----
template <bool FINAL>
__launch_bounds__(256, 2)
__global__ void k_mlp(const u16* __restrict__ A, const u16* __restrict__ wT1g,
                      const float* __restrict__ b1, const u16* __restrict__ wT2g,
                      const float* __restrict__ b2, u16* __restrict__ H,
                      const u16* __restrict__ xbg, const u16* __restrict__ h1g,
                      const u16* __restrict__ h2g, const u16* __restrict__ fwTc,
                      const float* __restrict__ fb, float* __restrict__ out) {
    __shared__ u16 Tb[128 * 128];    // 32 KB
    __shared__ u16 wbuf[128 * 128];  // 32 KB
    uint4* Tb4 = (uint4*)Tb;
    uint4* wb4 = (uint4*)wbuf;
    int tid = threadIdx.x;
    int r0 = blockIdx.x * 128;
    int wave = tid >> 6, lane = tid & 63, l16 = lane & 15, quad = lane >> 4;

    // stage W1^T (swizzled)
    {
        const uint4* g = (const uint4*)wT1g;
        for (int i = tid; i < 2048; i += 256) {
            int n = i >> 4, ch = i & 15;
            wb4[n * 16 + ((ch + n) & 15)] = g[i];
        }
    }

    // A-fragments straight from global (no cross-wave reuse)
    AB a[2][4];
#pragma unroll
    for (int s = 0; s < 2; ++s) {
        int row = r0 + wave * 32 + s * 16 + l16;
#pragma unroll
        for (int kb = 0; kb < 4; ++kb) {
            if (row < NNODES)
                a[s][kb].u4 = *(const uint4*)&A[row * 128 + kb * 32 + quad * 8];
            else
                a[s][kb].u4 = make_uint4(0, 0, 0, 0);
        }
    }
    __syncthreads();

    f32x4 acc[2][8];
#pragma unroll
    for (int col = 0; col < 8; ++col) {
        float bv = b1[col * 16 + l16];
        acc[0][col] = (f32x4){bv, bv, bv, bv};
        acc[1][col] = (f32x4){bv, bv, bv, bv};
    }
#pragma unroll
    for (int col = 0; col < 8; ++col) {
#pragma unroll
        for (int kb = 0; kb < 4; ++kb) {
            AB b;
            int n = col * 16 + l16;
            b.u4 = wb4[n * 16 + ((kb * 4 + quad + n) & 15)];
            acc[0][col] = __builtin_amdgcn_mfma_f32_16x16x32_bf16(a[0][kb].f, b.f, acc[0][col], 0, 0, 0);
            acc[1][col] = __builtin_amdgcn_mfma_f32_16x16x32_bf16(a[1][kb].f, b.f, acc[1][col], 0, 0, 0);
        }
    }

    // T = relu -> Tb (swizzled scalar u16 stores)
#pragma unroll
    for (int s = 0; s < 2; ++s)
#pragma unroll
        for (int col = 0; col < 8; ++col)
#pragma unroll
            for (int r = 0; r < 4; ++r) {
                int row = wave * 32 + s * 16 + quad * 4 + r;
                int kcol = col * 16 + l16;
                int ch = kcol >> 3;
                Tb[row * 128 + ((ch + row) & 15) * 8 + (kcol & 7)] =
                    f2b(fmaxf(acc[s][col][r], 0.f));
            }
    __syncthreads();

    // stage W2^T (swizzled, overwrite wbuf)
    {
        const uint4* g = (const uint4*)wT2g;
        for (int i = tid; i < 2048; i += 256) {
            int n = i >> 4, ch = i & 15;
            wb4[n * 16 + ((ch + n) & 15)] = g[i];
        }
    }
    AB a2[2][4];
#pragma unroll
    for (int s = 0; s < 2; ++s) {
        int m = wave * 32 + s * 16 + l16;
#pragma unroll
        for (int kb = 0; kb < 4; ++kb)
            a2[s][kb].u4 = Tb4[m * 16 + ((kb * 4 + quad + m) & 15)];
    }
    __syncthreads();  // wbuf (W2) ready; Tb reads drained

#pragma unroll
    for (int col = 0; col < 8; ++col) {
        float bv = b2[col * 16 + l16];
        acc[0][col] = (f32x4){bv, bv, bv, bv};
        acc[1][col] = (f32x4){bv, bv, bv, bv};
    }
#pragma unroll
    for (int col = 0; col < 8; ++col) {
#pragma unroll
        for (int kb = 0; kb < 4; ++kb) {
            AB b;
            int n = col * 16 + l16;
            b.u4 = wb4[n * 16 + ((kb * 4 + quad + n) & 15)];
            acc[0][col] = __builtin_amdgcn_mfma_f32_16x16x32_bf16(a2[0][kb].f, b.f, acc[0][col], 0, 0, 0);
            acc[1][col] = __builtin_amdgcn_mfma_f32_16x16x32_bf16(a2[1][kb].f, b.f, acc[1][col], 0, 0, 0);
        }
    }

    // h = relu -> Tb (Tb reads a2 drained at pre-GEMM2 barrier; GEMM2 reads only wbuf)
#pragma unroll
    for (int s = 0; s < 2; ++s)
#pragma unroll
        for (int col = 0; col < 8; ++col)
#pragma unroll
            for (int r = 0; r < 4; ++r) {
                int row = wave * 32 + s * 16 + quad * 4 + r;
                int kcol = col * 16 + l16;
                int ch = kcol >> 3;
                Tb[row * 128 + ((ch + row) & 15) * 8 + (kcol & 7)] =
                    f2b(fmaxf(acc[s][col][r], 0.f));
            }

    if constexpr (!FINAL) {
        __syncthreads();  // Tb (h) ready
        // coalesced copy Tb -> H (de-swizzle); stays cached (read by next k_agg)
        for (int i = tid; i < 2048; i += 256) {
            int r = i >> 4, ch = i & 15;
            int grow = r0 + r;
            if (grow < NNODES)
                *(uint4*)&H[grow * 128 + ch * 8] = Tb4[r * 16 + ((ch + r) & 15)];
        }
    } else {
        // ---- fused final projection: out = concat(x,h1,h2,h3) @ fw + fb ----
#pragma unroll
        for (int col = 0; col < 8; ++col) {
            float bv = fb[col * 16 + l16];
            acc[0][col] = (f32x4){bv, bv, bv, bv};
            acc[1][col] = (f32x4){bv, bv, bv, bv};
        }
        const u16* chin[3] = {xbg, h1g, h2g};
        AB afN[2][4];
#pragma unroll
        for (int s = 0; s < 2; ++s) {  // prefetch chunk 0 (xb)
            int row = r0 + wave * 32 + s * 16 + l16;
#pragma unroll
            for (int kb = 0; kb < 4; ++kb)
                afN[s][kb].u4 = (row < NNODES)
                                    ? *(const uint4*)&xbg[row * 128 + kb * 32 + quad * 8]
                                    : make_uint4(0, 0, 0, 0);
        }
#pragma unroll
        for (int chn = 0; chn < 4; ++chn) {
            __syncthreads();  // prev wbuf MFMA reads drained; (chn0) Tb h3 stores visible
            {
                const uint4* g = (const uint4*)(fwTc + chn * 16384);
                for (int i = tid; i < 2048; i += 256) {
                    int n = i >> 4, ch = i & 15;
                    wb4[n * 16 + ((ch + n) & 15)] = g[i];
                }
            }
            AB af[2][4];
#pragma unroll
            for (int s = 0; s < 2; ++s)
#pragma unroll
                for (int kb = 0; kb < 4; ++kb) af[s][kb] = afN[s][kb];
            if (chn < 2) {  // prefetch next global chunk (h1 or h2)
                const u16* cp = chin[chn + 1];
#pragma unroll
                for (int s = 0; s < 2; ++s) {
                    int row = r0 + wave * 32 + s * 16 + l16;
#pragma unroll
                    for (int kb = 0; kb < 4; ++kb)
                        afN[s][kb].u4 = (row < NNODES)
                                            ? *(const uint4*)&cp[row * 128 + kb * 32 + quad * 8]
                                            : make_uint4(0, 0, 0, 0);
                }
            } else if (chn == 2) {  // prefetch h3 from Tb (stable throughout FINAL)
#pragma unroll
                for (int s = 0; s < 2; ++s) {
                    int m = wave * 32 + s * 16 + l16;
#pragma unroll
                    for (int kb = 0; kb < 4; ++kb)
                        afN[s][kb].u4 = Tb4[m * 16 + ((kb * 4 + quad + m) & 15)];
                }
            }
            __syncthreads();  // wbuf (fw chunk) ready
#pragma unroll
            for (int col = 0; col < 8; ++col) {
#pragma unroll
                for (int kb = 0; kb < 4; ++kb) {
                    AB b;
                    int n = col * 16 + l16;
                    b.u4 = wb4[n * 16 + ((kb * 4 + quad + n) & 15)];
                    acc[0][col] = __builtin_amdgcn_mfma_f32_16x16x32_bf16(af[0][kb].f, b.f, acc[0][col], 0, 0, 0);
                    acc[1][col] = __builtin_amdgcn_mfma_f32_16x16x32_bf16(af[1][kb].f, b.f, acc[1][col], 0, 0, 0);
                }
            }
        }
#pragma unroll
        for (int s = 0; s < 2; ++s)
#pragma unroll
            for (int col = 0; col < 8; ++col)
#pragma unroll
                for (int r = 0; r < 4; ++r) {
                    int row = r0 + wave * 32 + s * 16 + quad * 4 + r;
                    if (row < NNODES)
                        __builtin_nontemporal_store(acc[s][col][r],
                                                    &out[row * 128 + col * 16 + l16]);
                }
    }
}

extern "C" void kernel_launch(void* const* d_in, const int* in_sizes, int n_in,
                              void* d_out, int out_size, void* d_ws, size_t ws_size,
                              hipStream_t stream) {
    const float* x   = (const float*)d_in[0];
    const int*   ei  = (const int*)d_in[1];
    const float* W1  = (const float*)d_in[2];
    const float* b1  = (const float*)d_in[3];
    const float* W2  = (const float*)d_in[4];
    const float* b2  = (const float*)d_in[5];
    const float* eps = (const float*)d_in[6];
    const float* fw  = (const float*)d_in[7];
    const float* fb  = (const float*)d_in[8];
    float* out = (float*)d_out;

    const int* srcA = ei;
    const int* dstA = ei + NEDGES;

    char* p = (char*)d_ws;
    size_t off = 0;
    auto take = [&](size_t bytes) {
        char* r = p + off;
        off = (off + bytes + 255) & ~(size_t)255;
        return r;
    };
    int* rp   = (int*)take((NNODES + 1) * sizeof(int));
    int* cnt  = (int*)take((NNODES + 1) * sizeof(int));  // [NNODES] = scan arrival counter
    int* bsum = (int*)take(256 * sizeof(int));
    int* epos = (int*)take(NEDGES * sizeof(int));
    int* srcs = (int*)take(NEDGES * sizeof(int));
    u16* wT1  = (u16*)take(3 * 16384 * sizeof(u16));
    u16* wT2  = (u16*)take(3 * 16384 * sizeof(u16));
    u16* fwTc = (u16*)take(4 * 16384 * sizeof(u16));
    u16* xb   = (u16*)take((size_t)NNODES * D * sizeof(u16));
    u16* zb   = (u16*)take((size_t)NNODES * D * sizeof(u16));
    u16* hb1  = (u16*)take((size_t)NNODES * D * sizeof(u16));
    u16* hb2  = (u16*)take((size_t)NNODES * D * sizeof(u16));
    (void)ws_size; (void)in_sizes; (void)n_in; (void)out_size;

    (void)hipMemsetAsync(cnt, 0, (NNODES + 1) * sizeof(int), stream);

    int nb = (NNODES + 255) / 256;  // 196
    k_prep<<<(NNODES * 32 + 255) / 256, 256, 0, stream>>>(W1, W2, fw, x, dstA,
                                                          wT1, wT2, fwTc, (uint2*)xb,
                                                          cnt, epos);
    k_scan1<<<nb, 256, 0, stream>>>(cnt, rp, bsum, cnt + NNODES);
    k_scatter<<<(NEDGES + 255) / 256, 256, 0, stream>>>(srcA, dstA, rp, bsum, epos, srcs);

    int gm = (NNODES + 127) / 128;  // 391
    // layer 1
    k_agg<<<NNODES * 16 / 256, 256, 0, stream>>>((const uint4*)xb, rp, bsum, srcs, eps + 0, (uint4*)zb);
    k_mlp<false><<<gm, 256, 0, stream>>>(zb, wT1, b1, wT2, b2, hb1,
                                         nullptr, nullptr, nullptr, nullptr, nullptr, nullptr);
    // layer 2
    k_agg<<<NNODES * 16 / 256, 256, 0, stream>>>((const uint4*)hb1, rp, bsum, srcs, eps + 1, (uint4*)zb);
    k_mlp<false><<<gm, 256, 0, stream>>>(zb, wT1 + 16384, b1 + D, wT2 + 16384, b2 + D, hb2,
                                         nullptr, nullptr, nullptr, nullptr, nullptr, nullptr);
    // layer 3 + fused final projection
    k_agg<<<NNODES * 16 / 256, 256, 0, stream>>>((const uint4*)hb2, rp, bsum, srcs, eps + 2, (uint4*)zb);
    k_mlp<true><<<gm, 256, 0, stream>>>(zb, wT1 + 2 * 16384, b1 + 2 * D,
                                        wT2 + 2 * 16384, b2 + 2 * D, nullptr,
                                        xb, hb1, hb2, fwTc, fb, out);
}